// Round 1
// baseline (1235.338 us; speedup 1.0000x reference)
//
#include <hip/hip_runtime.h>
#include <hip/hip_bf16.h>
#include <stdint.h>

namespace {

constexpr int kNX = 1024, kNY = 1024, kT = 512, kTP = 512, kD = 128, kC = 8;
constexpr int kK = kTP * kD;            // 65536 flattened contraction dim
constexpr int SPLITK = 8;
constexpr int KCH = kK / SPLITK;        // 8192 per z-block
constexpr int BK = 32;                  // one 16x16x32 MFMA per K-step
constexpr int NKS = KCH / BK;           // 256 K-steps per block

typedef short bf16x8 __attribute__((ext_vector_type(8)));
typedef float f32x4 __attribute__((ext_vector_type(4)));

// ---------------- workspace layout (bytes) ----------------
constexpr size_t OFF_YB  = 0;                                   // Y bf16   [NY][TP][D]  128MB
constexpr size_t OFF_XP  = OFF_YB + (size_t)kNY * kK * 2;       // XP bf16  [NX][TP][D]  128MB
constexpr size_t OFF_YS  = OFF_XP + (size_t)kNX * kK * 2;       // YS f32   [NY][TP]     2MB
constexpr size_t OFF_ROW = OFF_YS + (size_t)kNY * kTP * 4;      // row f32  [C][T]
constexpr size_t OFF_COL = OFF_ROW + (size_t)kC * kT * 4;       // col f32  [C][TP]
constexpr size_t OFF_C1  = OFF_COL + (size_t)kC * kTP * 4;      // C1 f32   [NX]
constexpr size_t OFF_C2  = OFF_C1 + (size_t)kNX * 4;            // C2 f32   [C][NY]
constexpr size_t OFF_CNT = OFF_C2 + (size_t)kC * kNY * 4;       // cnt i32  [C][TP]
constexpr size_t OFF_TL  = OFF_CNT + (size_t)kC * kTP * 4;      // tlist u16 [C][TP][512]  4MB

__device__ __forceinline__ void gload16(const __hip_bfloat16* g, __hip_bfloat16* l) {
    __builtin_amdgcn_global_load_lds(
        (const __attribute__((address_space(1))) unsigned int*)g,
        (__attribute__((address_space(3))) unsigned int*)l, 16, 0, 0);
}

// ---- pi preprocessing: row sums, col sums, column-CSR of the 0/1 path ----
__global__ void pi_prep(const float* __restrict__ pi, float* __restrict__ row,
                        float* __restrict__ col, int* __restrict__ cnt,
                        unsigned short* __restrict__ tlist) {
    const int c = blockIdx.x;
    const int p = threadIdx.x;          // 512 threads, one per column
    __shared__ float lds_row[kT];
    for (int t = p; t < kT; t += 512) lds_row[t] = 0.f;
    __syncthreads();
    const float* pic = pi + (size_t)c * kT * kTP;
    float csum = 0.f;
    int n = 0;
    unsigned short* tl = tlist + (((size_t)c * kTP + p) << 9);
    for (int t = 0; t < kT; ++t) {
        float v = pic[(size_t)t * kTP + p];     // coalesced across p
        if (v != 0.f) {
            csum += v;
            tl[n++] = (unsigned short)t;
            atomicAdd(&lds_row[t], v);
        }
    }
    col[c * kTP + p] = csum;
    cnt[c * kTP + p] = n;
    __syncthreads();
    for (int t = p; t < kT; t += 512) row[c * kT + t] = lds_row[t];
}

// ---- Y prep: bf16 convert + per-(j,p) squared norms ----
__global__ void y_prep(const float* __restrict__ Y, __hip_bfloat16* __restrict__ YB,
                       float* __restrict__ YS) {
    const int j = blockIdx.x;
    const int tid = threadIdx.x;
    const int wv = tid >> 6, lane = tid & 63;
    const float* Yj = Y + (size_t)j * kTP * kD;
    __hip_bfloat16* YBj = YB + (size_t)j * kTP * kD;
    for (int p = wv; p < kTP; p += 4) {
        float2 y = *(const float2*)(Yj + p * kD + lane * 2);
        __hip_bfloat162 hb;
        hb.x = __float2bfloat16(y.x);
        hb.y = __float2bfloat16(y.y);
        *(__hip_bfloat162*)(YBj + p * kD + lane * 2) = hb;
        float s = y.x * y.x + y.y * y.y;
        #pragma unroll
        for (int o = 32; o; o >>= 1) s += __shfl_down(s, o);
        if (lane == 0) YS[(size_t)j * kTP + p] = s;
    }
}

// ---- C2[c][j] = sum_p YS[j][p] * col[c][p] ----
__global__ void c2_kernel(const float* __restrict__ YS, const float* __restrict__ col,
                          float* __restrict__ C2) {
    const int j = blockIdx.x;
    const int lane = threadIdx.x;       // 64 threads
    const float* ys = YS + (size_t)j * kTP;
    for (int c = 0; c < kC; ++c) {
        float s = 0.f;
        for (int p = lane; p < kTP; p += 64) s += ys[p] * col[c * kTP + p];
        #pragma unroll
        for (int o = 32; o; o >>= 1) s += __shfl_down(s, o);
        if (lane == 0) C2[c * kNY + j] = s;
    }
}

// ---- X prep: C1[i] + sparse XP[i] in bf16 ----
__global__ void x_prep(const float* __restrict__ X, const int* __restrict__ classe,
                       const float* __restrict__ row, const int* __restrict__ cnt,
                       const unsigned short* __restrict__ tlist,
                       float* __restrict__ C1, __hip_bfloat16* __restrict__ XPB) {
    const int i = blockIdx.x;
    const int tid = threadIdx.x;        // 256 threads
    const int c = classe[i];
    const float* Xi = X + (size_t)i * kT * kD;

    // phase A: C1[i] = sum_{t,d} X^2 * row[c][t]   (also warms L2 with X[i])
    float s = 0.f;
    const float* rowc = row + c * kT;
    for (int f = tid; f < kT * kD; f += 256) {
        float x = Xi[f];
        s += x * x * rowc[f >> 7];
    }
    #pragma unroll
    for (int o = 32; o; o >>= 1) s += __shfl_down(s, o);
    __shared__ float red[4];
    if ((tid & 63) == 0) red[tid >> 6] = s;
    __syncthreads();
    if (tid == 0) C1[i] = red[0] + red[1] + red[2] + red[3];

    // phase B: XP[i][p][d] = sum_{t in path col p} X[i][t][d]
    const int g = tid >> 7, d = tid & 127;
    __hip_bfloat16* XPi = XPB + (size_t)i * kTP * kD;
    for (int p = g; p < kTP; p += 2) {
        const int base = ((c * kTP + p) << 9);
        const int n = cnt[c * kTP + p];
        float a = 0.f;
        for (int k = 0; k < n; ++k) {
            int t = tlist[base + k];
            a += Xi[t * kD + d];
        }
        XPi[p * kD + d] = __float2bfloat16(a);
    }
}

// ---- out init: C1[i] + C2[classe[i]][j] ----
__global__ void init_out(const float* __restrict__ C1, const float* __restrict__ C2,
                         const int* __restrict__ classe, float* __restrict__ out) {
    const int i = blockIdx.x;
    const float c1 = C1[i];
    const float* c2 = C2 + (size_t)classe[i] * kNY;
    float* o = out + (size_t)i * kNY;
    for (int j = threadIdx.x; j < kNY; j += 256) o[j] = c1 + c2[j];
}

// ---- C3 GEMM: out -= 2 * XP @ Y^T   (bf16 MFMA, split-K, atomic accumulate) ----
__global__ __launch_bounds__(256) void gemm_c3(const __hip_bfloat16* __restrict__ A,
                                               const __hip_bfloat16* __restrict__ B,
                                               float* __restrict__ out) {
    __shared__ __align__(16) __hip_bfloat16 ldsA[128 * BK];
    __shared__ __align__(16) __hip_bfloat16 ldsB[128 * BK];
    const int tid = threadIdx.x;
    const int wv = tid >> 6, lane = tid & 63;
    const int wr = wv >> 1, wc = wv & 1;            // 2x2 wave grid, 64x64 per wave
    const int rowBase = blockIdx.y * 128;
    const int colBase = blockIdx.x * 128;
    const int k0base = blockIdx.z * KCH;

    f32x4 acc[4][4] = {};

    const int koff = (lane >> 4) * 8;               // k offset within BK
    const int rloc = lane & 15;

    for (int ks = 0; ks < NKS; ++ks) {
        const int k0 = k0base + ks * BK;
        // stage A and B tiles: 2 rounds x 256 threads x 16B each
        #pragma unroll
        for (int q = 0; q < 2; ++q) {
            const int idx = q * 256 + tid;
            const int r = idx >> 2, kc = idx & 3;
            gload16(A + ((size_t)(rowBase + r) * kK + k0 + kc * 8),
                    &ldsA[(q * 256 + wv * 64) * 8]);
            gload16(B + ((size_t)(colBase + r) * kK + k0 + kc * 8),
                    &ldsB[(q * 256 + wv * 64) * 8]);
        }
        __syncthreads();

        bf16x8 af[4], bfr[4];
        #pragma unroll
        for (int m = 0; m < 4; ++m)
            af[m] = *(const bf16x8*)&ldsA[(wr * 64 + m * 16 + rloc) * BK + koff];
        #pragma unroll
        for (int n = 0; n < 4; ++n)
            bfr[n] = *(const bf16x8*)&ldsB[(wc * 64 + n * 16 + rloc) * BK + koff];
        #pragma unroll
        for (int m = 0; m < 4; ++m)
            #pragma unroll
            for (int n = 0; n < 4; ++n)
                acc[m][n] = __builtin_amdgcn_mfma_f32_16x16x32_bf16(af[m], bfr[n], acc[m][n], 0, 0, 0);
        __syncthreads();
    }

    // epilogue: out -= 2*acc  (fp32 atomics; split-K partials race benignly)
    #pragma unroll
    for (int m = 0; m < 4; ++m) {
        #pragma unroll
        for (int n = 0; n < 4; ++n) {
            #pragma unroll
            for (int jj = 0; jj < 4; ++jj) {
                const int R = rowBase + wr * 64 + m * 16 + (lane >> 4) * 4 + jj;
                const int Cc = colBase + wc * 64 + n * 16 + (lane & 15);
                atomicAdd(&out[(size_t)R * kNY + Cc], -2.0f * acc[m][n][jj]);
            }
        }
    }
}

} // namespace

extern "C" void kernel_launch(void* const* d_in, const int* in_sizes, int n_in,
                              void* d_out, int out_size, void* d_ws, size_t ws_size,
                              hipStream_t stream) {
    const float* X = (const float*)d_in[0];
    const float* Y = (const float*)d_in[1];
    const float* pi = (const float*)d_in[2];
    const int* classe = (const int*)d_in[3];
    float* out = (float*)d_out;

    char* ws = (char*)d_ws;
    __hip_bfloat16* YB = (__hip_bfloat16*)(ws + OFF_YB);
    __hip_bfloat16* XPB = (__hip_bfloat16*)(ws + OFF_XP);
    float* YS = (float*)(ws + OFF_YS);
    float* row = (float*)(ws + OFF_ROW);
    float* col = (float*)(ws + OFF_COL);
    float* C1 = (float*)(ws + OFF_C1);
    float* C2 = (float*)(ws + OFF_C2);
    int* cnt = (int*)(ws + OFF_CNT);
    unsigned short* tlist = (unsigned short*)(ws + OFF_TL);

    pi_prep<<<kC, 512, 0, stream>>>(pi, row, col, cnt, tlist);
    y_prep<<<kNY, 256, 0, stream>>>(Y, YB, YS);
    c2_kernel<<<kNY, 64, 0, stream>>>(YS, col, C2);
    x_prep<<<kNX, 256, 0, stream>>>(X, classe, row, cnt, tlist, C1, XPB);
    init_out<<<kNX, 256, 0, stream>>>(C1, C2, classe, out);
    dim3 grid(kNY / 128, kNX / 128, SPLITK);
    gemm_c3<<<grid, 256, 0, stream>>>(XPB, YB, out);
}

// Round 2
// 555.058 us; speedup vs baseline: 2.2256x; 2.2256x over previous
//
#include <hip/hip_runtime.h>
#include <hip/hip_bf16.h>
#include <stdint.h>

namespace {

constexpr int kNX = 1024, kNY = 1024, kT = 512, kTP = 512, kD = 128, kC = 8;
constexpr int kK = kTP * kD;            // 65536 flattened contraction dim
constexpr int SPLITK = 8;
constexpr int KCH = kK / SPLITK;        // 8192 per z-block
constexpr int BK = 32;                  // one 16x16x32 MFMA per K-step
constexpr int NKS = KCH / BK;           // 256 K-steps per block

typedef short bf16x8 __attribute__((ext_vector_type(8)));
typedef float f32x4 __attribute__((ext_vector_type(4)));

// ---------------- workspace layout (bytes) ----------------
constexpr size_t OFF_YB  = 0;                                   // Y bf16   [NY][TP][D]  128MB
constexpr size_t OFF_XP  = OFF_YB + (size_t)kNY * kK * 2;       // XP bf16  [NX][TP][D]  128MB
constexpr size_t OFF_YS  = OFF_XP + (size_t)kNX * kK * 2;       // YS f32   [NY][TP]     2MB
constexpr size_t OFF_TS  = OFF_YS + (size_t)kNY * kTP * 4;      // ts i32   [C][TP]
constexpr size_t OFF_TE  = OFF_TS + (size_t)kC * kTP * 4;       // te i32   [C][TP]
constexpr size_t OFF_C1  = OFF_TE + (size_t)kC * kTP * 4;       // C1 f32   [NX]
constexpr size_t OFF_C2  = OFF_C1 + (size_t)kNX * 4;            // C2 f32   [C][NY]

__device__ __forceinline__ void gload16(const __hip_bfloat16* g, __hip_bfloat16* l) {
    __builtin_amdgcn_global_load_lds(
        (const __attribute__((address_space(1))) unsigned int*)g,
        (__attribute__((address_space(3))) unsigned int*)l, 16, 0, 0);
}

__device__ __forceinline__ unsigned short bf(float x) {
    union { __hip_bfloat16 h; unsigned short u; } cv;
    cv.h = __float2bfloat16(x);
    return cv.u;
}

// ---- init: ts=INT_MAX, te=-1, C1=0 ----
__global__ void init_ranges(int* __restrict__ ts, int* __restrict__ te,
                            float* __restrict__ C1) {
    const int idx = blockIdx.x * 256 + threadIdx.x;
    if (idx < kC * kTP) { ts[idx] = 0x7fffffff; te[idx] = -1; }
    if (idx < kNX) C1[idx] = 0.f;
}

// ---- pi scan: per-column contiguous run [ts,te] of the 0/1 monotone path ----
__global__ void pi_scan(const float* __restrict__ pi, int* __restrict__ ts,
                        int* __restrict__ te) {
    const int c = blockIdx.y;
    const int tbase = blockIdx.x * 64;
    const int p = threadIdx.x;                  // 512 threads, one per column
    const float* pic = pi + (size_t)c * kT * kTP;
    int tmin = 0x7fffffff, tmax = -1;
    for (int tt = 0; tt < 64; ++tt) {
        const int t = tbase + tt;
        float v = pic[(size_t)t * kTP + p];     // coalesced across p
        if (v != 0.f) { if (t < tmin) tmin = t; tmax = t; }
    }
    if (tmax >= 0) {
        atomicMin(&ts[c * kTP + p], tmin);
        atomicMax(&te[c * kTP + p], tmax);
    }
}

// ---- Y prep: bf16 convert (float4 loads) + per-(j,p) squared norms ----
__global__ void y_prep(const float* __restrict__ Y, __hip_bfloat16* __restrict__ YB,
                       float* __restrict__ YS) {
    const int j = blockIdx.x;
    const int tid = threadIdx.x;                // 256
    const int sub = tid & 31, g = tid >> 5;     // 8 rows concurrently
    const float4* Yj = (const float4*)(Y + (size_t)j * kTP * kD);
    unsigned short* YBj = (unsigned short*)YB + (size_t)j * kTP * kD;
    for (int p = g; p < kTP; p += 8) {
        float4 y = Yj[p * 32 + sub];
        ushort4 o;
        o.x = bf(y.x); o.y = bf(y.y); o.z = bf(y.z); o.w = bf(y.w);
        *(ushort4*)(YBj + p * kD + sub * 4) = o;
        float s = y.x * y.x + y.y * y.y + y.z * y.z + y.w * y.w;
        #pragma unroll
        for (int o2 = 16; o2; o2 >>= 1) s += __shfl_down(s, o2, 32);
        if (sub == 0) YS[(size_t)j * kTP + p] = s;
    }
}

// ---- C2[c][j] = sum_p YS[j][p] * (te-ts+1) ----
__global__ void c2_kernel(const float* __restrict__ YS, const int* __restrict__ ts,
                          const int* __restrict__ te, float* __restrict__ C2) {
    const int j = blockIdx.x;
    const int lane = threadIdx.x;               // 64 threads
    const float* ys = YS + (size_t)j * kTP;
    for (int c = 0; c < kC; ++c) {
        float s = 0.f;
        for (int p = lane; p < kTP; p += 64) {
            float colv = (float)(te[c * kTP + p] - ts[c * kTP + p] + 1);
            s += ys[p] * colv;
        }
        #pragma unroll
        for (int o = 32; o; o >>= 1) s += __shfl_down(s, o);
        if (lane == 0) C2[c * kNY + j] = s;
    }
}

// ---- XP gather over contiguous row runs + fused C1 ----
__global__ __launch_bounds__(256) void xp_kernel(const float* __restrict__ X,
                                                 const int* __restrict__ classe,
                                                 const int* __restrict__ ts,
                                                 const int* __restrict__ te,
                                                 float* __restrict__ C1,
                                                 __hip_bfloat16* __restrict__ XPB) {
    const int i = blockIdx.y, pc = blockIdx.x;  // sample, p-chunk of 64
    const int tid = threadIdx.x;
    const int sub = tid & 31, g = tid >> 5;     // 32 lanes per column, 8 columns
    const int c = classe[i];
    const float4* Xi = (const float4*)(X + (size_t)i * kT * kD);
    unsigned short* XPi = (unsigned short*)XPB + (size_t)i * kTP * kD;
    float sq = 0.f;
    #pragma unroll
    for (int q = 0; q < 8; ++q) {
        const int p = pc * 64 + q * 8 + g;
        const int t0 = ts[c * kTP + p], t1 = te[c * kTP + p];
        float ax = 0.f, ay = 0.f, az = 0.f, aw = 0.f;
        for (int t = t0; t <= t1; ++t) {
            float4 v = Xi[t * 32 + sub];
            ax += v.x; ay += v.y; az += v.z; aw += v.w;
            sq += v.x * v.x + v.y * v.y + v.z * v.z + v.w * v.w;
        }
        ushort4 o;
        o.x = bf(ax); o.y = bf(ay); o.z = bf(az); o.w = bf(aw);
        *(ushort4*)(XPi + p * kD + sub * 4) = o;
    }
    // block-reduce sq -> C1[i]
    #pragma unroll
    for (int o = 32; o; o >>= 1) sq += __shfl_down(sq, o);
    __shared__ float red[4];
    if ((tid & 63) == 0) red[tid >> 6] = sq;
    __syncthreads();
    if (tid == 0) atomicAdd(&C1[i], red[0] + red[1] + red[2] + red[3]);
}

// ---- out init: C1[i] + C2[classe[i]][j] ----
__global__ void init_out(const float* __restrict__ C1, const float* __restrict__ C2,
                         const int* __restrict__ classe, float* __restrict__ out) {
    const int i = blockIdx.x;
    const float c1 = C1[i];
    const float* c2 = C2 + (size_t)classe[i] * kNY;
    float* o = out + (size_t)i * kNY;
    for (int j = threadIdx.x; j < kNY; j += 256) o[j] = c1 + c2[j];
}

// ---- C3 GEMM: out -= 2 * XP @ Y^T   (bf16 MFMA, split-K, atomic accumulate) ----
__global__ __launch_bounds__(256) void gemm_c3(const __hip_bfloat16* __restrict__ A,
                                               const __hip_bfloat16* __restrict__ B,
                                               float* __restrict__ out) {
    __shared__ __align__(16) __hip_bfloat16 ldsA[128 * BK];
    __shared__ __align__(16) __hip_bfloat16 ldsB[128 * BK];
    const int tid = threadIdx.x;
    const int wv = tid >> 6, lane = tid & 63;
    const int wr = wv >> 1, wc = wv & 1;            // 2x2 wave grid, 64x64 per wave
    const int rowBase = blockIdx.y * 128;
    const int colBase = blockIdx.x * 128;
    const int k0base = blockIdx.z * KCH;

    f32x4 acc[4][4] = {};

    const int koff = (lane >> 4) * 8;               // k offset within BK
    const int rloc = lane & 15;

    for (int ks = 0; ks < NKS; ++ks) {
        const int k0 = k0base + ks * BK;
        #pragma unroll
        for (int q = 0; q < 2; ++q) {
            const int idx = q * 256 + tid;
            const int r = idx >> 2, kc = idx & 3;
            gload16(A + ((size_t)(rowBase + r) * kK + k0 + kc * 8),
                    &ldsA[(q * 256 + wv * 64) * 8]);
            gload16(B + ((size_t)(colBase + r) * kK + k0 + kc * 8),
                    &ldsB[(q * 256 + wv * 64) * 8]);
        }
        __syncthreads();

        bf16x8 af[4], bfr[4];
        #pragma unroll
        for (int m = 0; m < 4; ++m)
            af[m] = *(const bf16x8*)&ldsA[(wr * 64 + m * 16 + rloc) * BK + koff];
        #pragma unroll
        for (int n = 0; n < 4; ++n)
            bfr[n] = *(const bf16x8*)&ldsB[(wc * 64 + n * 16 + rloc) * BK + koff];
        #pragma unroll
        for (int m = 0; m < 4; ++m)
            #pragma unroll
            for (int n = 0; n < 4; ++n)
                acc[m][n] = __builtin_amdgcn_mfma_f32_16x16x32_bf16(af[m], bfr[n], acc[m][n], 0, 0, 0);
        __syncthreads();
    }

    #pragma unroll
    for (int m = 0; m < 4; ++m) {
        #pragma unroll
        for (int n = 0; n < 4; ++n) {
            #pragma unroll
            for (int jj = 0; jj < 4; ++jj) {
                const int R = rowBase + wr * 64 + m * 16 + (lane >> 4) * 4 + jj;
                const int Cc = colBase + wc * 64 + n * 16 + (lane & 15);
                atomicAdd(&out[(size_t)R * kNY + Cc], -2.0f * acc[m][n][jj]);
            }
        }
    }
}

} // namespace

extern "C" void kernel_launch(void* const* d_in, const int* in_sizes, int n_in,
                              void* d_out, int out_size, void* d_ws, size_t ws_size,
                              hipStream_t stream) {
    const float* X = (const float*)d_in[0];
    const float* Y = (const float*)d_in[1];
    const float* pi = (const float*)d_in[2];
    const int* classe = (const int*)d_in[3];
    float* out = (float*)d_out;

    char* ws = (char*)d_ws;
    __hip_bfloat16* YB = (__hip_bfloat16*)(ws + OFF_YB);
    __hip_bfloat16* XPB = (__hip_bfloat16*)(ws + OFF_XP);
    float* YS = (float*)(ws + OFF_YS);
    int* ts = (int*)(ws + OFF_TS);
    int* te = (int*)(ws + OFF_TE);
    float* C1 = (float*)(ws + OFF_C1);
    float* C2 = (float*)(ws + OFF_C2);

    init_ranges<<<(kC * kTP + 255) / 256, 256, 0, stream>>>(ts, te, C1);
    pi_scan<<<dim3(kT / 64, kC), kTP, 0, stream>>>(pi, ts, te);
    y_prep<<<kNY, 256, 0, stream>>>(Y, YB, YS);
    c2_kernel<<<kNY, 64, 0, stream>>>(YS, ts, te, C2);
    xp_kernel<<<dim3(8, kNX), 256, 0, stream>>>(X, classe, ts, te, C1, XPB);
    init_out<<<kNX, 256, 0, stream>>>(C1, C2, classe, out);
    dim3 grid(kNY / 128, kNX / 128, SPLITK);
    gemm_c3<<<grid, 256, 0, stream>>>(XPB, YB, out);
}